// Round 4
// baseline (6692.896 us; speedup 1.0000x reference)
//
#include <hip/hip_runtime.h>
#include <hip/hip_bf16.h>
#include <stdint.h>

#define BB   64
#define TT   2048
#define II   256
#define HH   256
#define G4   1024   // 4*H
#define NC   10
#define KR   112    // kpairs register-resident (of 128); rest in LDS

typedef _Float16 half2v __attribute__((ext_vector_type(2)));
typedef _Float16 half8v __attribute__((ext_vector_type(8)));
typedef float    float4v __attribute__((ext_vector_type(4)));

__device__ __forceinline__ float fdot2(uint32_t w, uint32_t h, float acc) {
  return __builtin_amdgcn_fdot2(__builtin_bit_cast(half2v, w),
                                __builtin_bit_cast(half2v, h), acc, false);
}
__device__ __forceinline__ float sigmf(float v) { return 1.f / (1.f + __expf(-v)); }
__device__ __forceinline__ float tanhf2(float v) { float e = __expf(2.f * v); return 1.f - 2.f / (e + 1.f); }

// Barrier WITHOUT vmcnt drain: keeps global prefetches in flight.
__device__ __forceinline__ void bar_lds() {
  asm volatile("s_waitcnt lgkmcnt(0)\n\ts_barrier" ::: "memory");
}

// ---------------------------------------------------------------------------
// K0a: WcT[g][i] = sum_j key[i][j] * W_ih[g][j]  (f16), biasc[g] = b_ih+b_hh
// ---------------------------------------------------------------------------
__global__ __launch_bounds__(1024) void prep_wc(
    const float* __restrict__ key, const float* __restrict__ Wih,
    const float* __restrict__ bih, const float* __restrict__ bhh,
    _Float16* __restrict__ WcT, float* __restrict__ biasc) {
  __shared__ float krow[II];
  const int i = blockIdx.x;
  const int g = threadIdx.x;
  if (g < II) krow[g] = key[(size_t)i * II + g];
  __syncthreads();
  const float4* w4 = (const float4*)(Wih + (size_t)g * II);
  float acc = 0.f;
#pragma unroll 8
  for (int j = 0; j < II / 4; ++j) {
    float4 w = w4[j];
    acc += w.x * krow[4 * j] + w.y * krow[4 * j + 1] + w.z * krow[4 * j + 2] + w.w * krow[4 * j + 3];
  }
  WcT[(size_t)g * II + i] = (_Float16)acc;
  if (i == 0) biasc[g] = bih[g] + bhh[g];
}

// ---------------------------------------------------------------------------
// K0c: pack W_hh. Thread h-index t owns gate rows {t, t+256, t+512, t+768}.
// uint4 per (kpair, t) = that kpair's f16-pair for the 4 rows.
//   kp <  KR -> wrg4[kp*256 + t]   (register-resident in lstm_seq)
//   kp >= KR -> wtl [(kp-KR)*256+t] (LDS-resident)
// ---------------------------------------------------------------------------
__global__ __launch_bounds__(256) void prep_whh(
    const float* __restrict__ Whh, uint4* __restrict__ wrg4, uint4* __restrict__ wtl) {
  const int id = blockIdx.x * 256 + threadIdx.x;   // 32768 = 128 kp * 256 t
  const int t  = id & 255;
  const int kp = id >> 8;                           // 0..127
  uint32_t d[4];
#pragma unroll
  for (int r = 0; r < 4; ++r) {
    const int g = t + r * 256;
    half2v h = {(_Float16)Whh[(size_t)g * HH + 2 * kp],
                (_Float16)Whh[(size_t)g * HH + 2 * kp + 1]};
    d[r] = __builtin_bit_cast(uint32_t, h);
  }
  uint4 v = {d[0], d[1], d[2], d[3]};
  if (kp < KR) wrg4[kp * 256 + t] = v;
  else         wtl[(kp - KR) * 256 + t] = v;
}

// ---------------------------------------------------------------------------
// K1: packed x-projection GEMM. Logical x_proj[m][g]; stored per row m as
//   1024 f16 at index 4*(g&255) + (g>>8): thread t's 4 gate-x values
//   (i,f,g,o of h-index t) are f16[4t..4t+3] = one aligned uint2.
// ---------------------------------------------------------------------------
__global__ __launch_bounds__(256) void gemm_xproj(
    const float* __restrict__ x, const _Float16* __restrict__ WcT,
    const float* __restrict__ biasc, _Float16* __restrict__ xpk) {
  __shared__ __align__(16) _Float16 Asm[128][40];
  __shared__ __align__(16) _Float16 Bsm[128][40];
  const int t = threadIdx.x;
  const int n0 = blockIdx.x * 128;
  const int m0 = blockIdx.y * 128;
  const int r = t >> 1;
  const int hoff = (t & 1) * 16;
  const int lane = t & 63, wave = t >> 6;
  const int quad = lane >> 4, l15 = lane & 15;
  const int mh = (wave & 1) * 64, nh = (wave >> 1) * 64;
  float4v zero = {0.f, 0.f, 0.f, 0.f};
  float4v acc[4][4];
#pragma unroll
  for (int a = 0; a < 4; ++a)
#pragma unroll
    for (int b = 0; b < 4; ++b) acc[a][b] = zero;

  for (int kt = 0; kt < 8; ++kt) {
    const int k0 = kt * 32;
    const float4* xa = (const float4*)(x + (size_t)(m0 + r) * II + k0 + hoff);
    float4 f0 = xa[0], f1 = xa[1], f2 = xa[2], f3 = xa[3];
    half8v lo = {(_Float16)f0.x, (_Float16)f0.y, (_Float16)f0.z, (_Float16)f0.w,
                 (_Float16)f1.x, (_Float16)f1.y, (_Float16)f1.z, (_Float16)f1.w};
    half8v hi = {(_Float16)f2.x, (_Float16)f2.y, (_Float16)f2.z, (_Float16)f2.w,
                 (_Float16)f3.x, (_Float16)f3.y, (_Float16)f3.z, (_Float16)f3.w};
    const half8v* bsrc = (const half8v*)(WcT + (size_t)(n0 + r) * II + k0 + hoff);
    half8v b0 = bsrc[0], b1 = bsrc[1];
    *(half8v*)&Asm[r][hoff]     = lo;
    *(half8v*)&Asm[r][hoff + 8] = hi;
    *(half8v*)&Bsm[r][hoff]     = b0;
    *(half8v*)&Bsm[r][hoff + 8] = b1;
    __syncthreads();
    half8v af[4], bf[4];
#pragma unroll
    for (int mt = 0; mt < 4; ++mt) af[mt] = *(const half8v*)&Asm[mh + mt * 16 + l15][quad * 8];
#pragma unroll
    for (int nt = 0; nt < 4; ++nt) bf[nt] = *(const half8v*)&Bsm[nh + nt * 16 + l15][quad * 8];
#pragma unroll
    for (int mt = 0; mt < 4; ++mt)
#pragma unroll
      for (int nt = 0; nt < 4; ++nt)
        acc[mt][nt] = __builtin_amdgcn_mfma_f32_16x16x32_f16(af[mt], bf[nt], acc[mt][nt], 0, 0, 0);
    __syncthreads();
  }
  _Float16* dst = xpk;
#pragma unroll
  for (int nt = 0; nt < 4; ++nt) {
    const int col = n0 + nh + nt * 16 + l15;
    const float bias = biasc[col];
    const int cslot = 4 * (col & 255) + (col >> 8);
#pragma unroll
    for (int mt = 0; mt < 4; ++mt) {
      const int mrow = m0 + mh + mt * 16 + quad * 4;
#pragma unroll
      for (int j = 0; j < 4; ++j)
        dst[(size_t)(mrow + j) * 1024 + cslot] = (_Float16)(acc[mt][nt][j] + bias);
    }
  }
}

// ---------------------------------------------------------------------------
// K2: sequential LSTM. 64 WGs x 256 threads (4 waves/CU, 1 wave/SIMD,
// 512 unified regs/thread). Thread t owns h-index t = gate rows
// {t, t+256, t+512, t+768}: all 4 gates combine THREAD-LOCALLY (no gsm,
// one barrier/step via h ping-pong). Weights: 448 dwords in regs,
// 16 kpairs (64 KB) in LDS. Per step per wave: 32 uniform h b128 reads,
// 16 tail b128 reads, 1 b16 h write, 1 coalesced global uint2 (prefetched).
// ---------------------------------------------------------------------------
__global__ __launch_bounds__(256, 1) void lstm_seq(
    const uint32_t* __restrict__ xpk, const uint4* __restrict__ wrg4,
    const uint4* __restrict__ wtl, float* __restrict__ hfin) {
  __shared__ __align__(16) uint4 wsm[(128 - KR) * 256];  // 64 KB
  __shared__ __align__(16) uint32_t hsm[2][128];         // ping-pong h (f16 pairs)
  const int t = threadIdx.x, blk = blockIdx.x;

  uint4 wv[KR];
#pragma unroll
  for (int k = 0; k < KR; ++k) wv[k] = wrg4[k * 256 + t];
#pragma unroll
  for (int k = 0; k < 128 - KR; ++k) wsm[k * 256 + t] = wtl[k * 256 + t];
  if (t < 128) hsm[0][t] = 0;
  float cst = 0.f, hlast = 0.f;
  const uint32_t* xp = xpk + (size_t)blk * TT * 512 + t * 2;
  uint2 xn = *(const uint2*)xp;
  __syncthreads();

  for (int ts = 0; ts < TT; ++ts) {
    const uint2 xw = xn;
    xn = *(const uint2*)(xp + (size_t)((ts < TT - 1) ? ts + 1 : ts) * 512);
    const uint4* h4 = (const uint4*)hsm[ts & 1];
    float a0 = 0.f, a1 = 0.f, a2 = 0.f, a3 = 0.f;
    float c0 = 0.f, c1 = 0.f, c2 = 0.f, c3 = 0.f;
#pragma unroll
    for (int cc = 0; cc < KR / 4; ++cc) {      // register-resident kpairs
      uint4 hc = h4[cc];
      uint4 w0 = wv[4 * cc + 0], w1 = wv[4 * cc + 1];
      uint4 w2 = wv[4 * cc + 2], w3 = wv[4 * cc + 3];
      a0 = fdot2(w0.x, hc.x, a0); a1 = fdot2(w0.y, hc.x, a1);
      a2 = fdot2(w0.z, hc.x, a2); a3 = fdot2(w0.w, hc.x, a3);
      c0 = fdot2(w1.x, hc.y, c0); c1 = fdot2(w1.y, hc.y, c1);
      c2 = fdot2(w1.z, hc.y, c2); c3 = fdot2(w1.w, hc.y, c3);
      a0 = fdot2(w2.x, hc.z, a0); a1 = fdot2(w2.y, hc.z, a1);
      a2 = fdot2(w2.z, hc.z, a2); a3 = fdot2(w2.w, hc.z, a3);
      c0 = fdot2(w3.x, hc.w, c0); c1 = fdot2(w3.y, hc.w, c1);
      c2 = fdot2(w3.z, hc.w, c2); c3 = fdot2(w3.w, hc.w, c3);
    }
    {   // LDS-resident tail: kpairs KR..127 use h4[28..31]
      uint4 h28 = h4[28], h29 = h4[29], h30 = h4[30], h31 = h4[31];
      const uint32_t hd[16] = {h28.x, h28.y, h28.z, h28.w, h29.x, h29.y, h29.z, h29.w,
                               h30.x, h30.y, h30.z, h30.w, h31.x, h31.y, h31.z, h31.w};
#pragma unroll
      for (int k = 0; k < 16; ++k) {
        uint4 w = wsm[k * 256 + t];
        if (k & 1) {
          c0 = fdot2(w.x, hd[k], c0); c1 = fdot2(w.y, hd[k], c1);
          c2 = fdot2(w.z, hd[k], c2); c3 = fdot2(w.w, hd[k], c3);
        } else {
          a0 = fdot2(w.x, hd[k], a0); a1 = fdot2(w.y, hd[k], a1);
          a2 = fdot2(w.z, hd[k], a2); a3 = fdot2(w.w, hd[k], a3);
        }
      }
    }
    half2v xif = __builtin_bit_cast(half2v, xw.x);   // (i, f) x-proj
    half2v xgo = __builtin_bit_cast(half2v, xw.y);   // (g, o) x-proj
    float ig = sigmf(a0 + c0 + (float)xif.x);
    float fg = sigmf(a1 + c1 + (float)xif.y);
    float gg = tanhf2(a2 + c2 + (float)xgo.x);
    float og = sigmf(a3 + c3 + (float)xgo.y);
    cst = fg * cst + ig * gg;
    hlast = og * tanhf2(cst);
    ((_Float16*)hsm[(ts + 1) & 1])[t] = (_Float16)hlast;
    bar_lds();
  }
  hfin[(size_t)blk * HH + t] = hlast;
}

// ---------------------------------------------------------------------------
// K3: out[b][c] = h_last[b] . W_cls[c] + b_cls[c]
// ---------------------------------------------------------------------------
__global__ __launch_bounds__(256) void cls_k(
    const float* __restrict__ hfin, const float* __restrict__ Wcls,
    const float* __restrict__ bcls, float* __restrict__ out) {
  __shared__ float part[4][NC];
  const int b = blockIdx.x, tid = threadIdx.x;
  const int lane = tid & 63, wave = tid >> 6;
  float hv = hfin[(size_t)b * HH + tid];
#pragma unroll
  for (int c = 0; c < NC; ++c) {
    float p = hv * Wcls[c * HH + tid];
#pragma unroll
    for (int off = 32; off >= 1; off >>= 1) p += __shfl_down(p, off, 64);
    if (lane == 0) part[wave][c] = p;
  }
  __syncthreads();
  if (tid < NC) {
    out[(size_t)b * NC + tid] =
        part[0][tid] + part[1][tid] + part[2][tid] + part[3][tid] + bcls[tid];
  }
}

// ---------------------------------------------------------------------------
extern "C" void kernel_launch(void* const* d_in, const int* in_sizes, int n_in,
                              void* d_out, int out_size, void* d_ws, size_t ws_size,
                              hipStream_t stream) {
  (void)in_sizes; (void)n_in; (void)out_size; (void)ws_size;
  const float* x    = (const float*)d_in[0];
  const float* key  = (const float*)d_in[1];
  const float* Wih  = (const float*)d_in[2];
  const float* Whh  = (const float*)d_in[3];
  const float* bih  = (const float*)d_in[4];
  const float* bhh  = (const float*)d_in[5];
  const float* Wcls = (const float*)d_in[6];
  const float* bcls = (const float*)d_in[7];
  float* out = (float*)d_out;

  char* ws = (char*)d_ws;
  size_t off = 0;
  uint32_t* xpk = (uint32_t*)(ws + off); off += (size_t)BB * TT * 512 * 4;     // 268 MB
  uint4* wrg4   = (uint4*)(ws + off);    off += (size_t)KR * 256 * 16;         // 448 KB
  uint4* wtl    = (uint4*)(ws + off);    off += (size_t)(128 - KR) * 256 * 16; // 64 KB
  _Float16* WcT = (_Float16*)(ws + off); off += (size_t)G4 * II * 2;
  float* biasc  = (float*)(ws + off);    off += (size_t)G4 * 4;
  float* hfin   = (float*)(ws + off);    off += (size_t)BB * HH * 4;

  hipLaunchKernelGGL(prep_wc,  dim3(II),  dim3(G4),  0, stream, key, Wih, bih, bhh, WcT, biasc);
  hipLaunchKernelGGL(prep_whh, dim3(128), dim3(256), 0, stream, Whh, wrg4, wtl);
  hipLaunchKernelGGL(gemm_xproj, dim3(G4 / 128, (BB * TT) / 128), dim3(256), 0, stream,
                     x, WcT, biasc, (_Float16*)xpk);
  hipLaunchKernelGGL(lstm_seq, dim3(BB), dim3(256), 0, stream, xpk, wrg4, wtl, hfin);
  hipLaunchKernelGGL(cls_k,    dim3(BB), dim3(256), 0, stream, hfin, Wcls, bcls, out);
}

// Round 5
// 4495.522 us; speedup vs baseline: 1.4888x; 1.4888x over previous
//
#include <hip/hip_runtime.h>
#include <hip/hip_bf16.h>
#include <stdint.h>

#define BB   64
#define TT   2048
#define II   256
#define HH   256
#define G4   1024   // 4*H
#define NC   10

typedef _Float16 half2v __attribute__((ext_vector_type(2)));
typedef _Float16 half8v __attribute__((ext_vector_type(8)));
typedef float    float4v __attribute__((ext_vector_type(4)));

__device__ __forceinline__ float fdot2(uint32_t w, uint32_t h, float acc) {
  return __builtin_amdgcn_fdot2(__builtin_bit_cast(half2v, w),
                                __builtin_bit_cast(half2v, h), acc, false);
}
__device__ __forceinline__ float sigmf(float v) { return 1.f / (1.f + __expf(-v)); }
__device__ __forceinline__ float tanhf2(float v) { float e = __expf(2.f * v); return 1.f - 2.f / (e + 1.f); }

// quad butterfly sum (VALU DPP, stays off the DS pipe)
__device__ __forceinline__ float qred(float v) {
  int a = __builtin_amdgcn_update_dpp(0, __builtin_bit_cast(int, v), 0xB1, 0xF, 0xF, true);
  float v2 = v + __builtin_bit_cast(float, a);
  int b = __builtin_amdgcn_update_dpp(0, __builtin_bit_cast(int, v2), 0x4E, 0xF, 0xF, true);
  return v2 + __builtin_bit_cast(float, b);
}

// Barrier WITHOUT vmcnt drain: keeps global prefetches in flight.
__device__ __forceinline__ void bar_lds() {
  asm volatile("s_waitcnt lgkmcnt(0)\n\ts_barrier" ::: "memory");
}

// ---------------------------------------------------------------------------
// K0a: WcT[g][i] = sum_j key[i][j] * W_ih[g][j]  (f16), biasc[g] = b_ih+b_hh
// ---------------------------------------------------------------------------
__global__ __launch_bounds__(1024) void prep_wc(
    const float* __restrict__ key, const float* __restrict__ Wih,
    const float* __restrict__ bih, const float* __restrict__ bhh,
    _Float16* __restrict__ WcT, float* __restrict__ biasc) {
  __shared__ float krow[II];
  const int i = blockIdx.x;
  const int g = threadIdx.x;
  if (g < II) krow[g] = key[(size_t)i * II + g];
  __syncthreads();
  const float4* w4 = (const float4*)(Wih + (size_t)g * II);
  float acc = 0.f;
#pragma unroll 8
  for (int j = 0; j < II / 4; ++j) {
    float4 w = w4[j];
    acc += w.x * krow[4 * j] + w.y * krow[4 * j + 1] + w.z * krow[4 * j + 2] + w.w * krow[4 * j + 3];
  }
  WcT[(size_t)g * II + i] = (_Float16)acc;
  if (i == 0) biasc[g] = bih[g] + bhh[g];
}

// ---------------------------------------------------------------------------
// K0c: pack W_hh for the quad-K-split LSTM.
// Thread t = 4q+s (t<512): quad q owns h-indices {2q,2q+1} (8 gate rows),
// lane s owns kpair slice [32s,32s+32) = h-chunks 8s..8s+7, iterated in
// rotated order c_j = 8s + ((j+2s)&7) for bank-conflict-free broadcast.
// Slot (j,r): uint4 = kpairs 4c_j..4c_j+3 of row(r) = 2q+(r&1)+256*(r>>1).
//   j<6  -> wrg4[(j*8+r)*512+t]   (register-resident)
//   j>=6 -> wtl[((j-6)*8+r)*512+t] (LDS-resident)
// ---------------------------------------------------------------------------
__global__ __launch_bounds__(256) void prep_whh(
    const float* __restrict__ Whh, uint4* __restrict__ wrg4, uint4* __restrict__ wtl) {
  const int id = blockIdx.x * 256 + threadIdx.x;   // 32768 = 64 slots * 512 t
  const int t = id & 511;
  const int slot = id >> 9;                         // 0..63
  const int j = slot >> 3, r = slot & 7;
  const int q = t >> 2, s = t & 3;
  const int c = 8 * s + ((j + 2 * s) & 7);
  const int row = 2 * q + (r & 1) + 256 * (r >> 1);
  uint32_t d[4];
#pragma unroll
  for (int k = 0; k < 4; ++k) {
    const int kp = 4 * c + k;
    half2v h = {(_Float16)Whh[(size_t)row * HH + 2 * kp],
                (_Float16)Whh[(size_t)row * HH + 2 * kp + 1]};
    d[k] = __builtin_bit_cast(uint32_t, h);
  }
  uint4 v = {d[0], d[1], d[2], d[3]};
  if (j < 6) wrg4[(j * 8 + r) * 512 + t] = v;
  else       wtl[((j - 6) * 8 + r) * 512 + t] = v;
}

// ---------------------------------------------------------------------------
// K1: packed x-projection GEMM. Logical x_proj[m][col], col = h + 256*gate.
// Stored per row m as 1024 f16; slot = (h>>1)*8 + (h&1)*4 + gate, so quad q's
// 8 values {i,f,g,o}x{h=2q,2q+1} are f16[8q..8q+7] = one aligned uint4.
// ---------------------------------------------------------------------------
__global__ __launch_bounds__(256) void gemm_xproj(
    const float* __restrict__ x, const _Float16* __restrict__ WcT,
    const float* __restrict__ biasc, _Float16* __restrict__ xpk) {
  __shared__ __align__(16) _Float16 Asm[128][40];
  __shared__ __align__(16) _Float16 Bsm[128][40];
  const int t = threadIdx.x;
  const int n0 = blockIdx.x * 128;
  const int m0 = blockIdx.y * 128;
  const int r = t >> 1;
  const int hoff = (t & 1) * 16;
  const int lane = t & 63, wave = t >> 6;
  const int quad = lane >> 4, l15 = lane & 15;
  const int mh = (wave & 1) * 64, nh = (wave >> 1) * 64;
  float4v zero = {0.f, 0.f, 0.f, 0.f};
  float4v acc[4][4];
#pragma unroll
  for (int a = 0; a < 4; ++a)
#pragma unroll
    for (int b = 0; b < 4; ++b) acc[a][b] = zero;

  for (int kt = 0; kt < 8; ++kt) {
    const int k0 = kt * 32;
    const float4* xa = (const float4*)(x + (size_t)(m0 + r) * II + k0 + hoff);
    float4 f0 = xa[0], f1 = xa[1], f2 = xa[2], f3 = xa[3];
    half8v lo = {(_Float16)f0.x, (_Float16)f0.y, (_Float16)f0.z, (_Float16)f0.w,
                 (_Float16)f1.x, (_Float16)f1.y, (_Float16)f1.z, (_Float16)f1.w};
    half8v hi = {(_Float16)f2.x, (_Float16)f2.y, (_Float16)f2.z, (_Float16)f2.w,
                 (_Float16)f3.x, (_Float16)f3.y, (_Float16)f3.z, (_Float16)f3.w};
    const half8v* bsrc = (const half8v*)(WcT + (size_t)(n0 + r) * II + k0 + hoff);
    half8v b0 = bsrc[0], b1 = bsrc[1];
    *(half8v*)&Asm[r][hoff]     = lo;
    *(half8v*)&Asm[r][hoff + 8] = hi;
    *(half8v*)&Bsm[r][hoff]     = b0;
    *(half8v*)&Bsm[r][hoff + 8] = b1;
    __syncthreads();
    half8v af[4], bf[4];
#pragma unroll
    for (int mt = 0; mt < 4; ++mt) af[mt] = *(const half8v*)&Asm[mh + mt * 16 + l15][quad * 8];
#pragma unroll
    for (int nt = 0; nt < 4; ++nt) bf[nt] = *(const half8v*)&Bsm[nh + nt * 16 + l15][quad * 8];
#pragma unroll
    for (int mt = 0; mt < 4; ++mt)
#pragma unroll
      for (int nt = 0; nt < 4; ++nt)
        acc[mt][nt] = __builtin_amdgcn_mfma_f32_16x16x32_f16(af[mt], bf[nt], acc[mt][nt], 0, 0, 0);
    __syncthreads();
  }
  _Float16* dst = xpk;
#pragma unroll
  for (int nt = 0; nt < 4; ++nt) {
    const int col = n0 + nh + nt * 16 + l15;
    const float bias = biasc[col];
    const int h = col & 255, gate = col >> 8;
    const int cslot = (h >> 1) * 8 + (h & 1) * 4 + gate;
#pragma unroll
    for (int mt = 0; mt < 4; ++mt) {
      const int mrow = m0 + mh + mt * 16 + quad * 4;
#pragma unroll
      for (int j = 0; j < 4; ++j)
        dst[(size_t)(mrow + j) * 1024 + cslot] = (_Float16)(acc[mt][nt][j] + bias);
    }
  }
}

// ---------------------------------------------------------------------------
// K2: sequential LSTM, quad-K-split. 64 WGs x 512 threads (2 waves/SIMD).
// Thread 4q+s: partial dots over kpair slice s for the 8 gate rows of
// h-indices {2q,2q+1}; DPP quad butterfly combines slices; gates computed
// redundantly in all 4 quad lanes; lane s==0 publishes h (1 ds_write).
// Weights: 192 dwords/thread in regs, 64 in LDS (128 KB). Per wave per step:
// 8 uniform h b128 (staggered, conflict-free), 16 tail b128, 1 write,
// 1 global uint4 (prefetched; never drained - custom barrier).
// ---------------------------------------------------------------------------
__global__ __launch_bounds__(512, 2) void lstm_seq(
    const uint32_t* __restrict__ xpk, const uint4* __restrict__ wrg4,
    const uint4* __restrict__ wtl, float* __restrict__ hfin) {
  __shared__ __align__(16) uint32_t hbuf[2][128];   // ping-pong h (f16 pairs)
  __shared__ __align__(16) uint4 wsm[16 * 512];     // 128 KB weight tail
  const int t = threadIdx.x, blk = blockIdx.x;
  const int q = t >> 2, s = t & 3;

  uint4 wv[48];
#pragma unroll
  for (int k = 0; k < 48; ++k) wv[k] = wrg4[k * 512 + t];
#pragma unroll
  for (int k = 0; k < 16; ++k) wsm[k * 512 + t] = wtl[k * 512 + t];
  if (t < 128) hbuf[0][t] = 0;

  // per-lane rotated chunk byte offsets (conflict-free h broadcast)
  int coff[8];
#pragma unroll
  for (int j = 0; j < 8; ++j) coff[j] = (8 * s + ((j + 2 * s) & 7)) * 16;

  float c0 = 0.f, c1 = 0.f, h0v = 0.f, h1v = 0.f;
  const uint32_t* xp = xpk + (size_t)blk * TT * 512;   // 512 dwords per step
  uint4 xn = *(const uint4*)(xp + 4 * q);              // quad slot prefetch
  __syncthreads();

  for (int ts = 0; ts < TT; ++ts) {
    const uint4 xw = xn;
    xn = *(const uint4*)(xp + (size_t)((ts < TT - 1) ? ts + 1 : ts) * 512 + 4 * q);
    const char* hc_base = (const char*)hbuf[ts & 1];
    float acc[8] = {0.f, 0.f, 0.f, 0.f, 0.f, 0.f, 0.f, 0.f};
#pragma unroll
    for (int j = 0; j < 8; ++j) {
      uint4 hc = *(const uint4*)(hc_base + coff[j]);
      if (j < 6) {
#pragma unroll
        for (int r = 0; r < 8; ++r) {
          uint4 w = wv[j * 8 + r];
          acc[r] = fdot2(w.x, hc.x, acc[r]);
          acc[r] = fdot2(w.y, hc.y, acc[r]);
          acc[r] = fdot2(w.z, hc.z, acc[r]);
          acc[r] = fdot2(w.w, hc.w, acc[r]);
        }
      } else {
#pragma unroll
        for (int r = 0; r < 8; ++r) {
          uint4 w = wsm[((j - 6) * 8 + r) * 512 + t];
          acc[r] = fdot2(w.x, hc.x, acc[r]);
          acc[r] = fdot2(w.y, hc.y, acc[r]);
          acc[r] = fdot2(w.z, hc.z, acc[r]);
          acc[r] = fdot2(w.w, hc.w, acc[r]);
        }
      }
    }
    // quad reduction: all 4 lanes get full sums (r: 0=i0 1=i1 2=f0 3=f1 4=g0 5=g1 6=o0 7=o1)
    float red[8];
#pragma unroll
    for (int r = 0; r < 8; ++r) red[r] = qred(acc[r]);
    // x-proj slot: {i0,f0,g0,o0, i1,f1,g1,o1}
    half2v xa = __builtin_bit_cast(half2v, xw.x);   // i0,f0
    half2v xb = __builtin_bit_cast(half2v, xw.y);   // g0,o0
    half2v xc = __builtin_bit_cast(half2v, xw.z);   // i1,f1
    half2v xd = __builtin_bit_cast(half2v, xw.w);   // g1,o1
    float i0 = sigmf(red[0] + (float)xa.x);
    float f0 = sigmf(red[2] + (float)xa.y);
    float g0 = tanhf2(red[4] + (float)xb.x);
    float o0 = sigmf(red[6] + (float)xb.y);
    float i1 = sigmf(red[1] + (float)xc.x);
    float f1 = sigmf(red[3] + (float)xc.y);
    float g1 = tanhf2(red[5] + (float)xd.x);
    float o1 = sigmf(red[7] + (float)xd.y);
    c0 = f0 * c0 + i0 * g0;
    c1 = f1 * c1 + i1 * g1;
    h0v = o0 * tanhf2(c0);
    h1v = o1 * tanhf2(c1);
    if (s == 0) {
      half2v hp = {(_Float16)h0v, (_Float16)h1v};
      hbuf[(ts + 1) & 1][q] = __builtin_bit_cast(uint32_t, hp);
    }
    bar_lds();
  }
  if (s == 0) {
    hfin[(size_t)blk * HH + 2 * q]     = h0v;
    hfin[(size_t)blk * HH + 2 * q + 1] = h1v;
  }
}

// ---------------------------------------------------------------------------
// K3: out[b][c] = h_last[b] . W_cls[c] + b_cls[c]
// ---------------------------------------------------------------------------
__global__ __launch_bounds__(256) void cls_k(
    const float* __restrict__ hfin, const float* __restrict__ Wcls,
    const float* __restrict__ bcls, float* __restrict__ out) {
  __shared__ float part[4][NC];
  const int b = blockIdx.x, tid = threadIdx.x;
  const int lane = tid & 63, wave = tid >> 6;
  float hv = hfin[(size_t)b * HH + tid];
#pragma unroll
  for (int c = 0; c < NC; ++c) {
    float p = hv * Wcls[c * HH + tid];
#pragma unroll
    for (int off = 32; off >= 1; off >>= 1) p += __shfl_down(p, off, 64);
    if (lane == 0) part[wave][c] = p;
  }
  __syncthreads();
  if (tid < NC) {
    out[(size_t)b * NC + tid] =
        part[0][tid] + part[1][tid] + part[2][tid] + part[3][tid] + bcls[tid];
  }
}

// ---------------------------------------------------------------------------
extern "C" void kernel_launch(void* const* d_in, const int* in_sizes, int n_in,
                              void* d_out, int out_size, void* d_ws, size_t ws_size,
                              hipStream_t stream) {
  (void)in_sizes; (void)n_in; (void)out_size; (void)ws_size;
  const float* x    = (const float*)d_in[0];
  const float* key  = (const float*)d_in[1];
  const float* Wih  = (const float*)d_in[2];
  const float* Whh  = (const float*)d_in[3];
  const float* bih  = (const float*)d_in[4];
  const float* bhh  = (const float*)d_in[5];
  const float* Wcls = (const float*)d_in[6];
  const float* bcls = (const float*)d_in[7];
  float* out = (float*)d_out;

  char* ws = (char*)d_ws;
  size_t off = 0;
  uint32_t* xpk = (uint32_t*)(ws + off); off += (size_t)BB * TT * 512 * 4;  // 268 MB
  uint4* wrg4   = (uint4*)(ws + off);    off += (size_t)48 * 512 * 16;      // 384 KB
  uint4* wtl    = (uint4*)(ws + off);    off += (size_t)16 * 512 * 16;      // 128 KB
  _Float16* WcT = (_Float16*)(ws + off); off += (size_t)G4 * II * 2;
  float* biasc  = (float*)(ws + off);    off += (size_t)G4 * 4;
  float* hfin   = (float*)(ws + off);    off += (size_t)BB * HH * 4;

  hipLaunchKernelGGL(prep_wc,  dim3(II),  dim3(G4),  0, stream, key, Wih, bih, bhh, WcT, biasc);
  hipLaunchKernelGGL(prep_whh, dim3(128), dim3(256), 0, stream, Whh, wrg4, wtl);
  hipLaunchKernelGGL(gemm_xproj, dim3(G4 / 128, (BB * TT) / 128), dim3(256), 0, stream,
                     x, WcT, biasc, (_Float16*)xpk);
  hipLaunchKernelGGL(lstm_seq, dim3(BB), dim3(512), 0, stream, xpk, wrg4, wtl, hfin);
  hipLaunchKernelGGL(cls_k,    dim3(BB), dim3(256), 0, stream, hfin, Wcls, bcls, out);
}